// Round 3
// baseline (304.466 us; speedup 1.0000x reference)
//
#include <hip/hip_runtime.h>
#include <hip/hip_cooperative_groups.h>

// AttentionBlock: B=8, C=128, H=W=128, GROUPS=8, HEADS=8, HEAD_DIM=16
// R4: single cooperative kernel (grid 256 x 512thr, 1 block/CU), 5 phases:
//  A: per-block Gram partials over 512-spatial slab (bf16 MFMA, LDS-swizzled),
//     plain streaming stores (NO atomics).
//  B: all-block reduction of partials -> G[b], m[b].
//  C1 (8 blocks): stats -> A=w_in*s -> T=A@G -> S_h=T_h A_h^T + rank-1 -> softmax
//     -> sW, ss, t2v to global.   (exact R2 fold math, f32)
//  C2 (64 blocks, 8/batch): T2=blkdiag(W)@A in f32, M rows (16/block) via f32 VALU,
//     bias2. -> Mb bf16.
//  D: out = x + M@x + bias2 (MFMA, Xt swizzled; x re-read is L3-hot).
// grid.sync() between phases; zero host-side memset; one dispatch total.

#define NPOS 16384

typedef short short8 __attribute__((ext_vector_type(8)));   // 8 bf16
typedef float f32x4 __attribute__((ext_vector_type(4)));

__device__ __forceinline__ unsigned short f2bf(float f) {
    union { float f; unsigned u; } v; v.f = f;
    unsigned r = (v.u + 0x7fffu + ((v.u >> 16) & 1u)) >> 16;
    return (unsigned short)r;
}
__device__ __forceinline__ float bf2f(unsigned short u) {
    union { unsigned u; float f; } v; v.u = ((unsigned)u) << 16;
    return v.f;
}

__global__ __launch_bounds__(512, 2) void k_fused(
    const float* __restrict__ x,
    const float* __restrict__ gn_w, const float* __restrict__ gn_b,
    const float* __restrict__ w_in, const float* __restrict__ b_in,
    const float* __restrict__ w_out, const float* __restrict__ b_out,
    float* __restrict__ out,
    float* Gpart, float* mpart, float* G, float* mvG,
    float* ssg, float* sWg, float* t2vg, float* bias2,
    unsigned short* Mb) {

    __shared__ __align__(16) unsigned char SH[131072];
    __shared__ float b2s[128];

    const int t = threadIdx.x;
    const int lane = t & 63, wv = t >> 6;
    const int q = lane >> 4, i16 = lane & 15;
    const int blk = blockIdx.x;
    const int b = blk >> 5, slab = blk & 31;
    const size_t d0 = (size_t)slab << 9;           // 512 spatial per slab

    cooperative_groups::grid_group grid = cooperative_groups::this_grid();

    // ================= Phase A: Gram partial over slab =================
    {
        unsigned short* Xs = (unsigned short*)SH;   // [c=128][d=512] bf16 swizzled
        const float* xb = x + (size_t)b * (128 * NPOS) + d0;
#pragma unroll
        for (int i = 0; i < 32; ++i) {
            int idx = t + i * 512;                  // float4 index over [128][128]
            int c = idx >> 7, d4 = idx & 127;
            float4 v = *((const float4*)(xb + (size_t)c * NPOS) + d4);
            ushort4 o;
            o.x = f2bf(v.x); o.y = f2bf(v.y); o.z = f2bf(v.z); o.w = f2bf(v.w);
            int g = d4 >> 1;                        // granule (8 ushorts)
            int sg = g ^ (c & 7);
            *(ushort4*)&Xs[c * 512 + (sg << 3) + ((d4 & 1) << 2)] = o;
        }
        __syncthreads();

        f32x4 acc[8];
        f32x4 macc = (f32x4){0.f, 0.f, 0.f, 0.f};
#pragma unroll
        for (int ct = 0; ct < 8; ++ct) acc[ct] = (f32x4){0.f, 0.f, 0.f, 0.f};
        const short8 ones = {(short)0x3F80, (short)0x3F80, (short)0x3F80, (short)0x3F80,
                             (short)0x3F80, (short)0x3F80, (short)0x3F80, (short)0x3F80};
        const int r0 = wv * 16 + i16;
#pragma unroll
        for (int ks = 0; ks < 16; ++ks) {
            int gd = ks * 4 + q;
            short8 af = *(const short8*)&Xs[r0 * 512 + ((gd ^ (r0 & 7)) << 3)];
            macc = __builtin_amdgcn_mfma_f32_16x16x32_bf16(af, ones, macc, 0, 0, 0);
#pragma unroll
            for (int ct = 0; ct < 8; ++ct) {
                int rb = ct * 16 + i16;
                short8 bf = *(const short8*)&Xs[rb * 512 + ((gd ^ (rb & 7)) << 3)];
                acc[ct] = __builtin_amdgcn_mfma_f32_16x16x32_bf16(af, bf, acc[ct], 0, 0, 0);
            }
        }
        float* gp = Gpart + (size_t)blk * 16384;
#pragma unroll
        for (int ct = 0; ct < 8; ++ct)
#pragma unroll
            for (int r = 0; r < 4; ++r)
                gp[(wv * 16 + q * 4 + r) * 128 + ct * 16 + i16] = acc[ct][r];
        if (i16 == 0) {
#pragma unroll
            for (int r = 0; r < 4; ++r)
                mpart[blk * 128 + wv * 16 + q * 4 + r] = macc[r];
        }
    }
    grid.sync();

    // ================= Phase B: reduce partials -> G, mvG =================
    {
        float sum = 0.f;
        size_t base = (size_t)(b * 32) * 16384 + slab * 512 + t;
#pragma unroll 4
        for (int s = 0; s < 32; ++s) sum += Gpart[base + (size_t)s * 16384];
        G[b * 16384 + slab * 512 + t] = sum;
        if (slab == 0 && t < 128) {
            float ms = 0.f;
#pragma unroll 4
            for (int s = 0; s < 32; ++s) ms += mpart[(b * 32 + s) * 128 + t];
            mvG[b * 128 + t] = ms;
        }
    }
    grid.sync();

    // ================= Phase C1 (8 blocks): fold to softmax =================
    if (slab == 0) {
        unsigned short* As = (unsigned short*)SH;              // 128*136 us
        unsigned short* Ts = (unsigned short*)(SH + 34816);    // 128*136 us
        float* sW  = (float*)(SH + 69632);                     // 2048 f32
        float* sm  = (float*)(SH + 77824);
        float* ss  = (float*)(SH + 78336);
        float* st  = (float*)(SH + 78848);
        float* sv  = (float*)(SH + 79360);
        float* su  = (float*)(SH + 79872);
        float* red = (float*)(SH + 80384);                     // [8][128]
        const float* Gb = G + b * 16384;

        if (t < 128) sm[t] = mvG[b * 128 + t];
        __syncthreads();
        if (t < 128) {
            int g = t >> 4;
            float s1 = 0.f, s2 = 0.f;
#pragma unroll
            for (int k = 0; k < 16; ++k) {
                int c = g * 16 + k;
                s1 += sm[c];
                s2 += Gb[c * 128 + c];
            }
            const float invN = 1.0f / 262144.0f;
            float mean = s1 * invN;
            float var = s2 * invN - mean * mean;
            float rstd = rsqrtf(var + 1e-5f);
            float s = gn_w[t] * rstd;
            ss[t] = s;
            st[t] = gn_b[t] - mean * s;
            ssg[b * 128 + t] = s;
        }
        __syncthreads();

        // A = w_in*s bf16 ; v,u partials
        {
            int c = t & 127, quarter = t >> 7;
            float v = 0.f, u = 0.f;
            const float* wr = w_in + c * 128 + quarter * 32;
            unsigned short* ar = &As[c * 136 + quarter * 32];
#pragma unroll
            for (int k = 0; k < 32; ++k) {
                int kg = quarter * 32 + k;
                float w = wr[k];
                float a = w * ss[kg];
                ar[k] = f2bf(a);
                v += w * st[kg];
                u += a * sm[kg];
            }
            red[quarter * 128 + c] = v;
            red[(4 + quarter) * 128 + c] = u;
        }
        // stage G -> bf16 Ts
        for (int idx = t; idx < 16384; idx += 512)
            Ts[(idx >> 7) * 136 + (idx & 127)] = f2bf(Gb[idx]);
        __syncthreads();
        if (t < 128) {
            sv[t] = b_in[t] + red[t] + red[128 + t] + red[256 + t] + red[384 + t];
            su[t] = red[512 + t] + red[640 + t] + red[768 + t] + red[896 + t];
        }
        __syncthreads();

        // T = A @ G
        f32x4 tacc[8];
#pragma unroll
        for (int ct = 0; ct < 8; ++ct) tacc[ct] = (f32x4){0.f, 0.f, 0.f, 0.f};
        const int rA = wv * 16 + i16;
#pragma unroll
        for (int ks = 0; ks < 4; ++ks) {
            short8 af = *(const short8*)&As[rA * 136 + ks * 32 + q * 8];
#pragma unroll
            for (int ct = 0; ct < 8; ++ct) {
                short8 gbf = *(const short8*)&Ts[(ct * 16 + i16) * 136 + ks * 32 + q * 8];
                tacc[ct] = __builtin_amdgcn_mfma_f32_16x16x32_bf16(af, gbf, tacc[ct], 0, 0, 0);
            }
        }
        __syncthreads();
#pragma unroll
        for (int ct = 0; ct < 8; ++ct)
#pragma unroll
            for (int r = 0; r < 4; ++r)
                Ts[(wv * 16 + q * 4 + r) * 136 + ct * 16 + i16] = f2bf(tacc[ct][r]);
        __syncthreads();

        // S + softmax (wave wv = head wv)
        {
            f32x4 sacc = (f32x4){0.f, 0.f, 0.f, 0.f};
#pragma unroll
            for (int ks = 0; ks < 4; ++ks) {
                short8 tf = *(const short8*)&Ts[rA * 136 + ks * 32 + q * 8];
                short8 af = *(const short8*)&As[rA * 136 + ks * 32 + q * 8];
                sacc = __builtin_amdgcn_mfma_f32_16x16x32_bf16(tf, af, sacc, 0, 0, 0);
            }
            int J = wv * 16 + i16;
            float vJ = sv[J], uJ = su[J];
#pragma unroll
            for (int r = 0; r < 4; ++r) {
                int I = wv * 16 + q * 4 + r;
                float val = (sacc[r] + su[I] * vJ + sv[I] * uJ + 16384.f * sv[I] * vJ) * 0.25f;
                float mx = val;
#pragma unroll
                for (int msk = 1; msk < 16; msk <<= 1) mx = fmaxf(mx, __shfl_xor(mx, msk));
                float e = __expf(val - mx);
                float sum = e;
#pragma unroll
                for (int msk = 1; msk < 16; msk <<= 1) sum += __shfl_xor(sum, msk);
                float wgt = e / sum;
                sW[I * 16 + i16] = wgt;
                sWg[b * 2048 + I * 16 + i16] = wgt;
            }
        }
        __syncthreads();
        // t2v = blkdiag(W) @ v
        if (t < 128) {
            int h = t >> 4;
            float a = 0.f;
#pragma unroll
            for (int j = 0; j < 16; ++j) a += sW[t * 16 + j] * sv[h * 16 + j];
            t2vg[b * 128 + t] = a;
        }
    }
    grid.sync();

    // ================= Phase C2 (64 blocks): T2 f32 -> M rows, bias2 =========
    if ((blk & 3) == 0) {
        int blkC = blk >> 2, bC = blkC >> 3, part = blkC & 7;
        unsigned short* As = (unsigned short*)SH;              // 128*136 us
        float* T2f = (float*)(SH + 34816);                     // 128*132 f32
        float* sW  = (float*)(SH + 102400);                    // 2048 f32
        float* ssl = (float*)(SH + 110592);                    // 128 f32

        for (int idx = t; idx < 2048; idx += 512) sW[idx] = sWg[bC * 2048 + idx];
        if (t < 128) ssl[t] = ssg[bC * 128 + t];
        __syncthreads();
        {
            int c = t & 127, quarter = t >> 7;
            const float* wr = w_in + c * 128 + quarter * 32;
            unsigned short* ar = &As[c * 136 + quarter * 32];
#pragma unroll
            for (int k = 0; k < 32; ++k) ar[k] = f2bf(wr[k] * ssl[quarter * 32 + k]);
        }
        __syncthreads();
        // T2 = blkdiag(W) @ A   (f32)
        {
            int o = t & 127, quarter = t >> 7;
            int h = o >> 4;
            float a32[32];
#pragma unroll
            for (int kk = 0; kk < 32; ++kk) a32[kk] = 0.f;
#pragma unroll
            for (int j = 0; j < 16; ++j) {
                float wj = sW[o * 16 + j];
                const ushort4* ar4 = (const ushort4*)&As[(h * 16 + j) * 136 + quarter * 32];
#pragma unroll
                for (int k4 = 0; k4 < 8; ++k4) {
                    ushort4 vv = ar4[k4];
                    a32[k4 * 4 + 0] += wj * bf2f(vv.x);
                    a32[k4 * 4 + 1] += wj * bf2f(vv.y);
                    a32[k4 * 4 + 2] += wj * bf2f(vv.z);
                    a32[k4 * 4 + 3] += wj * bf2f(vv.w);
                }
            }
#pragma unroll
            for (int kk = 0; kk < 32; ++kk) T2f[o * 132 + quarter * 32 + kk] = a32[kk];
        }
        __syncthreads();
        // M rows [part*16, part*16+16)  (f32 VALU, 4 outputs/thread)
        {
            int m0 = t * 4;
            int c = part * 16 + (m0 >> 7), k = m0 & 127;
            const float* wor = w_out + c * 128;
            float a0 = 0.f, a1 = 0.f, a2 = 0.f, a3 = 0.f;
#pragma unroll 4
            for (int o = 0; o < 128; ++o) {
                float w = wor[o];
                float4 vv = *(const float4*)&T2f[o * 132 + k];
                a0 += w * vv.x; a1 += w * vv.y; a2 += w * vv.z; a3 += w * vv.w;
            }
            ushort4 o4;
            o4.x = f2bf(a0); o4.y = f2bf(a1); o4.z = f2bf(a2); o4.w = f2bf(a3);
            *(ushort4*)&Mb[bC * 16384 + c * 128 + k] = o4;
        }
        if (part == 0 && t < 128) {
            float a = b_out[t];
            const float* wr = w_out + t * 128;
#pragma unroll 4
            for (int o = 0; o < 128; ++o) a += wr[o] * t2vg[bC * 128 + o];
            bias2[b * 128 + t] = a;   // b == bC here (blk==bC*8*... only when slab==0? no)
        }
    }
    grid.sync();

    // ================= Phase D: out = x + M@x + bias2 =================
    {
        unsigned short* Xt = (unsigned short*)SH;   // [p=512][k=128] bf16 swizzled
        if (t < 128) b2s[t] = bias2[b * 128 + t];
        const float* xb = x + (size_t)b * (128 * NPOS) + d0;
#pragma unroll
        for (int i = 0; i < 32; ++i) {
            int pch = i & 7, kq = (wv << 2) + (i >> 3);
            int p = (pch << 6) + lane;
            const float* col = xb + (size_t)(kq * 4) * NPOS + p;
            float a0 = col[0];
            float a1 = col[NPOS];
            float a2 = col[2 * NPOS];
            float a3 = col[3 * NPOS];
            ushort4 o; o.x = f2bf(a0); o.y = f2bf(a1); o.z = f2bf(a2); o.w = f2bf(a3);
            int g = kq >> 1;
            int sg = g ^ (p & 7);
            *(ushort4*)&Xt[p * 128 + (sg << 3) + ((kq & 1) << 2)] = o;
        }
        __syncthreads();

        const int cband = wv & 3, ph = wv >> 2;
        f32x4 acc[2][16];
#pragma unroll
        for (int a = 0; a < 2; ++a)
#pragma unroll
            for (int pt = 0; pt < 16; ++pt) acc[a][pt] = (f32x4){0.f, 0.f, 0.f, 0.f};

        const unsigned short* Mrow = Mb + (size_t)b * 16384;
#pragma unroll
        for (int ks = 0; ks < 4; ++ks) {
            short8 a0 = *(const short8*)&Mrow[(cband * 32 + i16) * 128 + ks * 32 + q * 8];
            short8 a1 = *(const short8*)&Mrow[(cband * 32 + 16 + i16) * 128 + ks * 32 + q * 8];
            int g = ks * 4 + q;
#pragma unroll
            for (int pt = 0; pt < 16; ++pt) {
                int pr = ph * 256 + pt * 16 + i16;
                short8 bb = *(const short8*)&Xt[pr * 128 + ((g ^ (pr & 7)) << 3)];
                acc[0][pt] = __builtin_amdgcn_mfma_f32_16x16x32_bf16(a0, bb, acc[0][pt], 0, 0, 0);
                acc[1][pt] = __builtin_amdgcn_mfma_f32_16x16x32_bf16(a1, bb, acc[1][pt], 0, 0, 0);
            }
        }

        float* ob = out + (size_t)b * (128 * NPOS) + d0;
#pragma unroll
        for (int a = 0; a < 2; ++a) {
            int cb = cband * 32 + a * 16 + q * 4;
#pragma unroll
            for (int pt = 0; pt < 16; ++pt) {
                int p = ph * 256 + pt * 16 + i16;
#pragma unroll
                for (int r = 0; r < 4; ++r) {
                    int c = cb + r;
                    ob[(size_t)c * NPOS + p] = acc[a][pt][r] + b2s[c] + xb[(size_t)c * NPOS + p];
                }
            }
        }
    }
}

extern "C" void kernel_launch(void* const* d_in, const int* in_sizes, int n_in,
                              void* d_out, int out_size, void* d_ws, size_t ws_size,
                              hipStream_t stream) {
    const float* x    = (const float*)d_in[0];
    const float* gn_w = (const float*)d_in[1];
    const float* gn_b = (const float*)d_in[2];
    const float* w_in = (const float*)d_in[3];
    const float* b_in = (const float*)d_in[4];
    const float* w_out= (const float*)d_in[5];
    const float* b_out= (const float*)d_in[6];
    float* out = (float*)d_out;

    // workspace layout (bytes), total ~17.8 MB:
    char* ws = (char*)d_ws;
    float* Gpart          = (float*)(ws + 0);          // 256*16384*4 = 16777216
    float* mpart          = (float*)(ws + 16777216);   // 256*128*4   = 131072
    float* G              = (float*)(ws + 16908288);   // 8*16384*4   = 524288
    float* mvG            = (float*)(ws + 17432576);   // 4096
    float* ssg            = (float*)(ws + 17436672);   // 4096
    float* sWg            = (float*)(ws + 17440768);   // 65536
    float* t2vg           = (float*)(ws + 17506304);   // 4096
    float* bias2          = (float*)(ws + 17510400);   // 4096
    unsigned short* Mb    = (unsigned short*)(ws + 17514496); // 262144

    void* args[] = {(void*)&x, (void*)&gn_w, (void*)&gn_b, (void*)&w_in,
                    (void*)&b_in, (void*)&w_out, (void*)&b_out, (void*)&out,
                    (void*)&Gpart, (void*)&mpart, (void*)&G, (void*)&mvG,
                    (void*)&ssg, (void*)&sWg, (void*)&t2vg, (void*)&bias2,
                    (void*)&Mb};
    hipLaunchCooperativeKernel((const void*)k_fused, dim3(256), dim3(512),
                               args, 0, stream);
}

// Round 4
// 171.886 us; speedup vs baseline: 1.7713x; 1.7713x over previous
//
#include <hip/hip_runtime.h>

// AttentionBlock: B=8, C=128, H=W=128, GROUPS=8, HEADS=8, HEAD_DIM=16
// R5: back to separate kernels (cooperative was -100us). Affine collapse:
//   G = x x^T, m = x@1  (k_gram: register-accumulated partials, NO atomics,
//                        LDS-transposed float4 partial stores; k_reduce sums)
//   k_fold (8 blocks, all-MFMA): stats -> A=w_in*s (+A^T) -> T=A@G -> S+softmax
//     -> P = w_out*blkdiag(W) (VALU) -> M = P@A (MFMA) -> Mb bf16, bias2 f32
//   k_out: out = x + M@x + bias2   (unchanged from R2)

#define NPOS 16384

typedef short short8 __attribute__((ext_vector_type(8)));   // 8 bf16
typedef float f32x4 __attribute__((ext_vector_type(4)));

__device__ __forceinline__ unsigned short f2bf(float f) {
    union { float f; unsigned u; } v; v.f = f;
    unsigned r = (v.u + 0x7fffu + ((v.u >> 16) & 1u)) >> 16;
    return (unsigned short)r;
}

// ---------------- K1: Gram partials, no atomics ----------------
// grid 512 = 8 b x 64 slabs of 256 pos; 2 chunks of 128 pos; LDS 66KB union.
__global__ __launch_bounds__(256, 2) void k_gram(const float* __restrict__ x,
                                                 float* __restrict__ Gpart,
                                                 float* __restrict__ mpart) {
    __shared__ __align__(16) unsigned char SH[67584];   // 32KB bf16 stage | 66KB f32 out

    const int t = threadIdx.x;
    const int lane = t & 63, wv = t >> 6;
    const int q = lane >> 4, i16 = lane & 15;
    const int blk = blockIdx.x;
    const int b = blk >> 6, slab = blk & 63;
    const size_t d0 = (size_t)slab << 8;      // 256 pos per block

    f32x4 acc[2][8];
    f32x4 macc[2];
#pragma unroll
    for (int a = 0; a < 2; ++a) {
        macc[a] = (f32x4){0.f, 0.f, 0.f, 0.f};
#pragma unroll
        for (int ct = 0; ct < 8; ++ct) acc[a][ct] = (f32x4){0.f, 0.f, 0.f, 0.f};
    }
    const short8 ones = {(short)0x3F80, (short)0x3F80, (short)0x3F80, (short)0x3F80,
                         (short)0x3F80, (short)0x3F80, (short)0x3F80, (short)0x3F80};
    const float* xb = x + (size_t)b * (128 * NPOS) + d0;
    unsigned short* Xs = (unsigned short*)SH;   // [c=128][k=128] bf16, granule-swizzled
    const int r0 = wv * 32 + i16, r1 = r0 + 16;

    for (int cc = 0; cc < 2; ++cc) {
        if (cc) __syncthreads();
        // stage chunk: x[c][d0 + cc*128 .. +128] -> bf16 LDS
#pragma unroll
        for (int i = 0; i < 16; ++i) {
            int idx = t + i * 256;              // float4 index over [128][32]
            int c = idx >> 5, d4 = idx & 31;
            float4 v = *((const float4*)(xb + (size_t)c * NPOS + cc * 128) + d4);
            ushort4 o;
            o.x = f2bf(v.x); o.y = f2bf(v.y); o.z = f2bf(v.z); o.w = f2bf(v.w);
            int g = d4 >> 1;                    // granule of 8 ushorts
            int sg = g ^ (c & 7);
            *(ushort4*)&Xs[c * 128 + (sg << 3) + ((d4 & 1) << 2)] = o;
        }
        __syncthreads();
#pragma unroll
        for (int ks = 0; ks < 4; ++ks) {
            int gd = ks * 4 + q;
            short8 a0 = *(const short8*)&Xs[r0 * 128 + ((gd ^ (r0 & 7)) << 3)];
            short8 a1 = *(const short8*)&Xs[r1 * 128 + ((gd ^ (r1 & 7)) << 3)];
            macc[0] = __builtin_amdgcn_mfma_f32_16x16x32_bf16(a0, ones, macc[0], 0, 0, 0);
            macc[1] = __builtin_amdgcn_mfma_f32_16x16x32_bf16(a1, ones, macc[1], 0, 0, 0);
#pragma unroll
            for (int ct = 0; ct < 8; ++ct) {
                int rb = ct * 16 + i16;
                short8 bb = *(const short8*)&Xs[rb * 128 + ((gd ^ (rb & 7)) << 3)];
                acc[0][ct] = __builtin_amdgcn_mfma_f32_16x16x32_bf16(a0, bb, acc[0][ct], 0, 0, 0);
                acc[1][ct] = __builtin_amdgcn_mfma_f32_16x16x32_bf16(a1, bb, acc[1][ct], 0, 0, 0);
            }
        }
    }
    // m partials (global, tiny)
    if (i16 == 0) {
#pragma unroll
        for (int a = 0; a < 2; ++a)
#pragma unroll
            for (int r = 0; r < 4; ++r)
                mpart[blk * 128 + wv * 32 + a * 16 + q * 4 + r] = macc[a][r];
    }
    __syncthreads();            // Xs dead -> reuse as f32 [128][132]

    float* Tf = (float*)SH;
#pragma unroll
    for (int a = 0; a < 2; ++a)
#pragma unroll
        for (int ct = 0; ct < 8; ++ct)
#pragma unroll
            for (int r = 0; r < 4; ++r)
                Tf[(wv * 32 + a * 16 + q * 4 + r) * 132 + ct * 16 + i16] = acc[a][ct][r];
    __syncthreads();
    float4* gp = (float4*)(Gpart + (size_t)blk * 16384);
#pragma unroll
    for (int i = 0; i < 16; ++i) {
        int fi = t + i * 256;               // float4 index over [128][32]
        int row = fi >> 5, c4 = fi & 31;
        gp[row * 32 + c4] = *(float4*)&Tf[row * 132 + c4 * 4];
    }
}

// ---------------- K1b: reduce partials -> G, mv ----------------
__global__ __launch_bounds__(256) void k_reduce(const float* __restrict__ Gpart,
                                                const float* __restrict__ mpart,
                                                float* __restrict__ G,
                                                float* __restrict__ mv) {
    int t = threadIdx.x;
    int fi = blockIdx.x * 256 + t;          // float4 index, 32768 total
    int b = fi >> 12, off4 = fi & 4095;
    const float4* Gp4 = (const float4*)Gpart;
    float4 s = (float4){0.f, 0.f, 0.f, 0.f};
#pragma unroll 8
    for (int sl = 0; sl < 64; ++sl) {
        float4 v = Gp4[(size_t)(b * 64 + sl) * 4096 + off4];
        s.x += v.x; s.y += v.y; s.z += v.z; s.w += v.w;
    }
    ((float4*)G)[fi] = s;
    if (blockIdx.x < 8 && t < 128) {
        float ms = 0.f;
#pragma unroll 8
        for (int sl = 0; sl < 64; ++sl) ms += mpart[(blockIdx.x * 64 + sl) * 128 + t];
        mv[blockIdx.x * 128 + t] = ms;
    }
}

// ---------------- K2: fold (all-MFMA) ----------------
// grid 8 (one block per batch), 512 threads (8 waves = 8 heads).
__global__ __launch_bounds__(512, 1) void k_fold(
    const float* __restrict__ G, const float* __restrict__ mvG,
    const float* __restrict__ gn_w, const float* __restrict__ gn_b,
    const float* __restrict__ w_in, const float* __restrict__ b_in,
    const float* __restrict__ w_out, const float* __restrict__ b_out,
    unsigned short* __restrict__ Mb, float* __restrict__ bias2) {
    __shared__ unsigned short As[128 * 136];   // A = w_in*s  (bf16)
    __shared__ unsigned short At[128 * 136];   // A^T
    __shared__ unsigned short Ts[128 * 136];   // G bf16 -> T bf16 -> P bf16
    __shared__ float sW[2048];
    __shared__ float sm[128], ss[128], st[128], sv[128], su[128];
    __shared__ float red[8][128];

    const int t = threadIdx.x;
    const int lane = t & 63, wv = t >> 6;
    const int q = lane >> 4, i16 = lane & 15;
    const int b = blockIdx.x;
    const float* Gb = G + b * 16384;

    if (t < 128) sm[t] = mvG[b * 128 + t];
    __syncthreads();
    if (t < 128) {
        int g = t >> 4;
        float s1 = 0.f, s2 = 0.f;
#pragma unroll
        for (int k = 0; k < 16; ++k) {
            int c = g * 16 + k;
            s1 += sm[c];
            s2 += Gb[c * 128 + c];
        }
        const float invN = 1.0f / 262144.0f;
        float mean = s1 * invN;
        float var = s2 * invN - mean * mean;
        float rstd = rsqrtf(var + 1e-5f);
        float s = gn_w[t] * rstd;
        ss[t] = s;
        st[t] = gn_b[t] - mean * s;
    }
    __syncthreads();

    // A (+A^T) bf16 ; v,u partials
    {
        int c = t & 127, quarter = t >> 7;
        float v = 0.f, u = 0.f;
        const float* wr = w_in + c * 128 + quarter * 32;
        unsigned short* ar = &As[c * 136 + quarter * 32];
#pragma unroll
        for (int k = 0; k < 32; ++k) {
            int kg = quarter * 32 + k;
            float w = wr[k];
            float a = w * ss[kg];
            unsigned short ab = f2bf(a);
            ar[k] = ab;
            At[kg * 136 + c] = ab;
            v += w * st[kg];
            u += a * sm[kg];
        }
        red[quarter][c] = v;
        red[4 + quarter][c] = u;
    }
    // stage G -> bf16 Ts
    for (int idx = t; idx < 16384; idx += 512)
        Ts[(idx >> 7) * 136 + (idx & 127)] = f2bf(Gb[idx]);
    __syncthreads();
    if (t < 128) {
        sv[t] = b_in[t] + red[0][t] + red[1][t] + red[2][t] + red[3][t];
        su[t] = red[4][t] + red[5][t] + red[6][t] + red[7][t];
    }
    __syncthreads();

    // T = A @ G  (G symmetric)
    f32x4 tacc[8];
#pragma unroll
    for (int ct = 0; ct < 8; ++ct) tacc[ct] = (f32x4){0.f, 0.f, 0.f, 0.f};
    const int rA = wv * 16 + i16;
#pragma unroll
    for (int ks = 0; ks < 4; ++ks) {
        short8 af = *(const short8*)&As[rA * 136 + ks * 32 + q * 8];
#pragma unroll
        for (int ct = 0; ct < 8; ++ct) {
            short8 gbf = *(const short8*)&Ts[(ct * 16 + i16) * 136 + ks * 32 + q * 8];
            tacc[ct] = __builtin_amdgcn_mfma_f32_16x16x32_bf16(af, gbf, tacc[ct], 0, 0, 0);
        }
    }
    __syncthreads();
#pragma unroll
    for (int ct = 0; ct < 8; ++ct)
#pragma unroll
        for (int r = 0; r < 4; ++r)
            Ts[(wv * 16 + q * 4 + r) * 136 + ct * 16 + i16] = f2bf(tacc[ct][r]);
    __syncthreads();

    // S_h = T_h A_h^T + rank-1 ; softmax -> sW (wave = head)
    {
        f32x4 sacc = (f32x4){0.f, 0.f, 0.f, 0.f};
#pragma unroll
        for (int ks = 0; ks < 4; ++ks) {
            short8 tf = *(const short8*)&Ts[rA * 136 + ks * 32 + q * 8];
            short8 af = *(const short8*)&As[rA * 136 + ks * 32 + q * 8];
            sacc = __builtin_amdgcn_mfma_f32_16x16x32_bf16(tf, af, sacc, 0, 0, 0);
        }
        int J = wv * 16 + i16;
        float vJ = sv[J], uJ = su[J];
#pragma unroll
        for (int r = 0; r < 4; ++r) {
            int I = wv * 16 + q * 4 + r;
            float val = (sacc[r] + su[I] * vJ + sv[I] * uJ + 16384.f * sv[I] * vJ) * 0.25f;
            float mx = val;
#pragma unroll
            for (int msk = 1; msk < 16; msk <<= 1) mx = fmaxf(mx, __shfl_xor(mx, msk));
            float e = __expf(val - mx);
            float sum = e;
#pragma unroll
            for (int msk = 1; msk < 16; msk <<= 1) sum += __shfl_xor(sum, msk);
            sW[I * 16 + i16] = e / sum;
        }
    }
    __syncthreads();

    // P = w_out * blkdiag(W)  (VALU f32 -> bf16 into Ts) ; bias2 = P@sv + b_out
    {
        int c = t & 127, grp = t >> 7;
        unsigned short* Ps = Ts;
        float pb = 0.f;
#pragma unroll
        for (int hh = 0; hh < 2; ++hh) {
            int h = grp * 2 + hh;
            float wrow[16];
#pragma unroll
            for (int i = 0; i < 16; ++i) wrow[i] = w_out[c * 128 + h * 16 + i];
#pragma unroll
            for (int j = 0; j < 16; ++j) {
                float val = 0.f;
#pragma unroll
                for (int i = 0; i < 16; ++i) val += wrow[i] * sW[(h * 16 + i) * 16 + j];
                Ps[c * 136 + h * 16 + j] = f2bf(val);
                pb += val * sv[h * 16 + j];
            }
        }
        red[grp][c] = pb;
    }
    __syncthreads();
    if (t < 128)
        bias2[b * 128 + t] = b_out[t] + red[0][t] + red[1][t] + red[2][t] + red[3][t];

    // M = P @ A  (MFMA: a = P rows, b = A^T rows)
    {
        f32x4 macc[8];
#pragma unroll
        for (int ct = 0; ct < 8; ++ct) macc[ct] = (f32x4){0.f, 0.f, 0.f, 0.f};
#pragma unroll
        for (int ks = 0; ks < 4; ++ks) {
            short8 pf = *(const short8*)&Ts[rA * 136 + ks * 32 + q * 8];
#pragma unroll
            for (int ct = 0; ct < 8; ++ct) {
                short8 atf = *(const short8*)&At[(ct * 16 + i16) * 136 + ks * 32 + q * 8];
                macc[ct] = __builtin_amdgcn_mfma_f32_16x16x32_bf16(pf, atf, macc[ct], 0, 0, 0);
            }
        }
        unsigned short* mb = Mb + (size_t)b * 16384;
#pragma unroll
        for (int ct = 0; ct < 8; ++ct)
#pragma unroll
            for (int r = 0; r < 4; ++r)
                mb[(wv * 16 + q * 4 + r) * 128 + ct * 16 + i16] = f2bf(macc[ct][r]);
    }
}

// ---------------- K3: out = x + M @ x + bias2 ----------------
__global__ __launch_bounds__(256, 4) void k_out(const float* __restrict__ x,
                                                const unsigned short* __restrict__ Mb,
                                                const float* __restrict__ bias2,
                                                float* __restrict__ out) {
    __shared__ unsigned short Xt[128 * 128];   // [p][k] bf16, granule-swizzled
    __shared__ float b2s[128];

    const int t = threadIdx.x;
    const int lane = t & 63, wv = t >> 6;
    const int q = lane >> 4, i16 = lane & 15;
    const int b = blockIdx.x >> 7;
    const int p0 = (blockIdx.x & 127) << 7;

    if (t < 128) b2s[t] = bias2[b * 128 + t];

    const float* xb = x + (size_t)b * (128 * NPOS) + p0;
#pragma unroll
    for (int i = 0; i < 16; ++i) {
        int p = ((i & 1) << 6) + lane;
        int kq = (wv << 3) + (i >> 1);
        const float* col = xb + (size_t)(kq * 4) * NPOS + p;
        float a0 = col[0];
        float a1 = col[NPOS];
        float a2 = col[2 * NPOS];
        float a3 = col[3 * NPOS];
        ushort4 o; o.x = f2bf(a0); o.y = f2bf(a1); o.z = f2bf(a2); o.w = f2bf(a3);
        int g = kq >> 1;
        int sg = g ^ (p & 7);
        *(ushort4*)&Xt[p * 128 + (sg << 3) + ((kq & 1) << 2)] = o;
    }
    __syncthreads();

    f32x4 acc[2][8];
#pragma unroll
    for (int a = 0; a < 2; ++a)
#pragma unroll
        for (int pt = 0; pt < 8; ++pt) acc[a][pt] = (f32x4){0.f, 0.f, 0.f, 0.f};

    const unsigned short* Mrow = Mb + (size_t)b * 16384;
#pragma unroll
    for (int ks = 0; ks < 4; ++ks) {
        short8 a0 = *(const short8*)&Mrow[(wv * 32 + i16) * 128 + ks * 32 + q * 8];
        short8 a1 = *(const short8*)&Mrow[(wv * 32 + 16 + i16) * 128 + ks * 32 + q * 8];
        int g = ks * 4 + q;
#pragma unroll
        for (int pt = 0; pt < 8; ++pt) {
            int pr = pt * 16 + i16;
            short8 bb = *(const short8*)&Xt[pr * 128 + ((g ^ (pr & 7)) << 3)];
            acc[0][pt] = __builtin_amdgcn_mfma_f32_16x16x32_bf16(a0, bb, acc[0][pt], 0, 0, 0);
            acc[1][pt] = __builtin_amdgcn_mfma_f32_16x16x32_bf16(a1, bb, acc[1][pt], 0, 0, 0);
        }
    }

    float* ob = out + (size_t)b * (128 * NPOS) + p0;
#pragma unroll
    for (int a = 0; a < 2; ++a) {
        int cb = wv * 32 + a * 16 + q * 4;
#pragma unroll
        for (int pt = 0; pt < 8; ++pt) {
            int p = pt * 16 + i16;
#pragma unroll
            for (int r = 0; r < 4; ++r) {
                int c = cb + r;
                ob[(size_t)c * NPOS + p] = acc[a][pt][r] + b2s[c] + xb[(size_t)c * NPOS + p];
            }
        }
    }
}

extern "C" void kernel_launch(void* const* d_in, const int* in_sizes, int n_in,
                              void* d_out, int out_size, void* d_ws, size_t ws_size,
                              hipStream_t stream) {
    const float* x    = (const float*)d_in[0];
    const float* gn_w = (const float*)d_in[1];
    const float* gn_b = (const float*)d_in[2];
    const float* w_in = (const float*)d_in[3];
    const float* b_in = (const float*)d_in[4];
    const float* w_out= (const float*)d_in[5];
    const float* b_out= (const float*)d_in[6];
    float* out = (float*)d_out;

    // workspace (bytes), total ~34.6 MB:
    char* ws = (char*)d_ws;
    float* Gpart          = (float*)(ws + 0);          // 512*16384*4 = 33554432
    float* mpart          = (float*)(ws + 33554432);   // 512*128*4   = 262144
    float* G              = (float*)(ws + 33816576);   // 8*16384*4   = 524288
    float* mvG            = (float*)(ws + 34340864);   // 4096
    float* bias2          = (float*)(ws + 34344960);   // 4096
    unsigned short* Mb    = (unsigned short*)(ws + 34349056); // 262144

    k_gram<<<dim3(512), dim3(256), 0, stream>>>(x, Gpart, mpart);
    k_reduce<<<dim3(128), dim3(256), 0, stream>>>(Gpart, mpart, G, mvG);
    k_fold<<<dim3(8), dim3(512), 0, stream>>>(G, mvG, gn_w, gn_b, w_in, b_in,
                                              w_out, b_out, Mb, bias2);
    k_out<<<dim3(1024), dim3(256), 0, stream>>>(x, Mb, bias2, out);
}

// Round 5
// 168.719 us; speedup vs baseline: 1.8046x; 1.0188x over previous
//
#include <hip/hip_runtime.h>

// AttentionBlock: B=8, C=128, H=W=128, GROUPS=8, HEADS=8, HEAD_DIM=16
// R6: affine collapse (R5 structure) + halved Gram-partial traffic:
//   k_gram: 256 blocks x 512 thr, 512-pos slab (2 staged chunks), reg-accumulated
//           Gram partial -> LDS transpose -> coalesced float4 store (16 MB total)
//   k_reduce: G = sum of 32 partials/batch (16 MB read)
//   k_fold (8 blocks, all-MFMA): stats -> A -> T=A@G -> S+softmax -> P -> M=P@A
//   k_out: out = x + M@x + bias2
// Harness workspace-poison fill (~40us, 256MiB) is fixed overhead outside our control.

#define NPOS 16384

typedef short short8 __attribute__((ext_vector_type(8)));   // 8 bf16
typedef float f32x4 __attribute__((ext_vector_type(4)));

__device__ __forceinline__ unsigned short f2bf(float f) {
    union { float f; unsigned u; } v; v.f = f;
    unsigned r = (v.u + 0x7fffu + ((v.u >> 16) & 1u)) >> 16;
    return (unsigned short)r;
}

// ---------------- K1: Gram partials, no atomics ----------------
// grid 256 = 8 b x 32 slabs of 512 pos; 2 chunks of 256 pos; 512 threads.
__global__ __launch_bounds__(512, 2) void k_gram(const float* __restrict__ x,
                                                 float* __restrict__ Gpart,
                                                 float* __restrict__ mpart) {
    __shared__ __align__(16) unsigned char SH[69632];   // 64KB bf16 stage | 67.6KB f32 out

    const int t = threadIdx.x;
    const int lane = t & 63, wv = t >> 6;
    const int q = lane >> 4, i16 = lane & 15;
    const int blk = blockIdx.x;
    const int b = blk >> 5, slab = blk & 31;
    const size_t d0 = (size_t)slab << 9;      // 512 pos per block

    f32x4 acc[8];
    f32x4 macc = (f32x4){0.f, 0.f, 0.f, 0.f};
#pragma unroll
    for (int ct = 0; ct < 8; ++ct) acc[ct] = (f32x4){0.f, 0.f, 0.f, 0.f};
    const short8 ones = {(short)0x3F80, (short)0x3F80, (short)0x3F80, (short)0x3F80,
                         (short)0x3F80, (short)0x3F80, (short)0x3F80, (short)0x3F80};
    const float* xb = x + (size_t)b * (128 * NPOS) + d0;
    unsigned short* Xs = (unsigned short*)SH;   // [c=128][d=256] bf16, granule-swizzled
    const int r0 = wv * 16 + i16;

    for (int cc = 0; cc < 2; ++cc) {
        if (cc) __syncthreads();
        // stage chunk: x[c][d0 + cc*256 .. +256] -> bf16 LDS
#pragma unroll
        for (int i = 0; i < 16; ++i) {
            int idx = t + i * 512;              // float4 index over [128][64]
            int c = idx >> 6, d4 = idx & 63;
            float4 v = *((const float4*)(xb + (size_t)c * NPOS + cc * 256) + d4);
            ushort4 o;
            o.x = f2bf(v.x); o.y = f2bf(v.y); o.z = f2bf(v.z); o.w = f2bf(v.w);
            int g = d4 >> 1;                    // granule of 8 ushorts (0..31)
            int sg = g ^ (c & 7);
            *(ushort4*)&Xs[c * 256 + (sg << 3) + ((d4 & 1) << 2)] = o;
        }
        __syncthreads();
#pragma unroll
        for (int ks = 0; ks < 8; ++ks) {
            int gd = ks * 4 + q;
            short8 af = *(const short8*)&Xs[r0 * 256 + ((gd ^ (r0 & 7)) << 3)];
            macc = __builtin_amdgcn_mfma_f32_16x16x32_bf16(af, ones, macc, 0, 0, 0);
#pragma unroll
            for (int ct = 0; ct < 8; ++ct) {
                int rb = ct * 16 + i16;
                short8 bb = *(const short8*)&Xs[rb * 256 + ((gd ^ (rb & 7)) << 3)];
                acc[ct] = __builtin_amdgcn_mfma_f32_16x16x32_bf16(af, bb, acc[ct], 0, 0, 0);
            }
        }
    }
    // m partials
    if (i16 == 0) {
#pragma unroll
        for (int r = 0; r < 4; ++r)
            mpart[blk * 128 + wv * 16 + q * 4 + r] = macc[r];
    }
    __syncthreads();            // Xs dead -> reuse as f32 [128][132]

    float* Tf = (float*)SH;
#pragma unroll
    for (int ct = 0; ct < 8; ++ct)
#pragma unroll
        for (int r = 0; r < 4; ++r)
            Tf[(wv * 16 + q * 4 + r) * 132 + ct * 16 + i16] = acc[ct][r];
    __syncthreads();
    float4* gp = (float4*)(Gpart + (size_t)blk * 16384);
#pragma unroll
    for (int i = 0; i < 8; ++i) {
        int fi = t + i * 512;               // float4 index over [128][32]
        int row = fi >> 5, c4 = fi & 31;
        gp[row * 32 + c4] = *(float4*)&Tf[row * 132 + c4 * 4];
    }
}

// ---------------- K1b: reduce partials -> G, mv ----------------
__global__ __launch_bounds__(256) void k_reduce(const float* __restrict__ Gpart,
                                                const float* __restrict__ mpart,
                                                float* __restrict__ G,
                                                float* __restrict__ mv) {
    int t = threadIdx.x;
    int fi = blockIdx.x * 256 + t;          // float4 index, 32768 total (grid 128)
    int b = fi >> 12, off4 = fi & 4095;
    const float4* Gp4 = (const float4*)Gpart;
    float4 s = (float4){0.f, 0.f, 0.f, 0.f};
#pragma unroll 8
    for (int sl = 0; sl < 32; ++sl) {
        float4 v = Gp4[(size_t)(b * 32 + sl) * 4096 + off4];
        s.x += v.x; s.y += v.y; s.z += v.z; s.w += v.w;
    }
    ((float4*)G)[fi] = s;
    if (blockIdx.x < 8 && t < 128) {
        float ms = 0.f;
#pragma unroll 8
        for (int sl = 0; sl < 32; ++sl) ms += mpart[(blockIdx.x * 32 + sl) * 128 + t];
        mv[blockIdx.x * 128 + t] = ms;
    }
}

// ---------------- K2: fold (all-MFMA) ----------------
// grid 8 (one block per batch), 512 threads (8 waves = 8 heads).
__global__ __launch_bounds__(512, 1) void k_fold(
    const float* __restrict__ G, const float* __restrict__ mvG,
    const float* __restrict__ gn_w, const float* __restrict__ gn_b,
    const float* __restrict__ w_in, const float* __restrict__ b_in,
    const float* __restrict__ w_out, const float* __restrict__ b_out,
    unsigned short* __restrict__ Mb, float* __restrict__ bias2) {
    __shared__ unsigned short As[128 * 136];   // A = w_in*s  (bf16)
    __shared__ unsigned short At[128 * 136];   // A^T
    __shared__ unsigned short Ts[128 * 136];   // G bf16 -> T bf16 -> P bf16
    __shared__ float sW[2048];
    __shared__ float sm[128], ss[128], st[128], sv[128], su[128];
    __shared__ float red[8][128];

    const int t = threadIdx.x;
    const int lane = t & 63, wv = t >> 6;
    const int q = lane >> 4, i16 = lane & 15;
    const int b = blockIdx.x;
    const float* Gb = G + b * 16384;

    if (t < 128) sm[t] = mvG[b * 128 + t];
    __syncthreads();
    if (t < 128) {
        int g = t >> 4;
        float s1 = 0.f, s2 = 0.f;
#pragma unroll
        for (int k = 0; k < 16; ++k) {
            int c = g * 16 + k;
            s1 += sm[c];
            s2 += Gb[c * 128 + c];
        }
        const float invN = 1.0f / 262144.0f;
        float mean = s1 * invN;
        float var = s2 * invN - mean * mean;
        float rstd = rsqrtf(var + 1e-5f);
        float s = gn_w[t] * rstd;
        ss[t] = s;
        st[t] = gn_b[t] - mean * s;
    }
    __syncthreads();

    // A (+A^T) bf16 ; v,u partials
    {
        int c = t & 127, quarter = t >> 7;
        float v = 0.f, u = 0.f;
        const float* wr = w_in + c * 128 + quarter * 32;
        unsigned short* ar = &As[c * 136 + quarter * 32];
#pragma unroll
        for (int k = 0; k < 32; ++k) {
            int kg = quarter * 32 + k;
            float w = wr[k];
            float a = w * ss[kg];
            unsigned short ab = f2bf(a);
            ar[k] = ab;
            At[kg * 136 + c] = ab;
            v += w * st[kg];
            u += a * sm[kg];
        }
        red[quarter][c] = v;
        red[4 + quarter][c] = u;
    }
    // stage G -> bf16 Ts
    for (int idx = t; idx < 16384; idx += 512)
        Ts[(idx >> 7) * 136 + (idx & 127)] = f2bf(Gb[idx]);
    __syncthreads();
    if (t < 128) {
        sv[t] = b_in[t] + red[0][t] + red[1][t] + red[2][t] + red[3][t];
        su[t] = red[4][t] + red[5][t] + red[6][t] + red[7][t];
    }
    __syncthreads();

    // T = A @ G  (G symmetric)
    f32x4 tacc[8];
#pragma unroll
    for (int ct = 0; ct < 8; ++ct) tacc[ct] = (f32x4){0.f, 0.f, 0.f, 0.f};
    const int rA = wv * 16 + i16;
#pragma unroll
    for (int ks = 0; ks < 4; ++ks) {
        short8 af = *(const short8*)&As[rA * 136 + ks * 32 + q * 8];
#pragma unroll
        for (int ct = 0; ct < 8; ++ct) {
            short8 gbf = *(const short8*)&Ts[(ct * 16 + i16) * 136 + ks * 32 + q * 8];
            tacc[ct] = __builtin_amdgcn_mfma_f32_16x16x32_bf16(af, gbf, tacc[ct], 0, 0, 0);
        }
    }
    __syncthreads();
#pragma unroll
    for (int ct = 0; ct < 8; ++ct)
#pragma unroll
        for (int r = 0; r < 4; ++r)
            Ts[(wv * 16 + q * 4 + r) * 136 + ct * 16 + i16] = f2bf(tacc[ct][r]);
    __syncthreads();

    // S_h = T_h A_h^T + rank-1 ; softmax -> sW (wave = head)
    {
        f32x4 sacc = (f32x4){0.f, 0.f, 0.f, 0.f};
#pragma unroll
        for (int ks = 0; ks < 4; ++ks) {
            short8 tf = *(const short8*)&Ts[rA * 136 + ks * 32 + q * 8];
            short8 af = *(const short8*)&As[rA * 136 + ks * 32 + q * 8];
            sacc = __builtin_amdgcn_mfma_f32_16x16x32_bf16(tf, af, sacc, 0, 0, 0);
        }
        int J = wv * 16 + i16;
        float vJ = sv[J], uJ = su[J];
#pragma unroll
        for (int r = 0; r < 4; ++r) {
            int I = wv * 16 + q * 4 + r;
            float val = (sacc[r] + su[I] * vJ + sv[I] * uJ + 16384.f * sv[I] * vJ) * 0.25f;
            float mx = val;
#pragma unroll
            for (int msk = 1; msk < 16; msk <<= 1) mx = fmaxf(mx, __shfl_xor(mx, msk));
            float e = __expf(val - mx);
            float sum = e;
#pragma unroll
            for (int msk = 1; msk < 16; msk <<= 1) sum += __shfl_xor(sum, msk);
            sW[I * 16 + i16] = e / sum;
        }
    }
    __syncthreads();

    // P = w_out * blkdiag(W)  (VALU f32 -> bf16 into Ts) ; bias2 = P@sv + b_out
    {
        int c = t & 127, grp = t >> 7;
        unsigned short* Ps = Ts;
        float pb = 0.f;
#pragma unroll
        for (int hh = 0; hh < 2; ++hh) {
            int h = grp * 2 + hh;
            float wrow[16];
#pragma unroll
            for (int i = 0; i < 16; ++i) wrow[i] = w_out[c * 128 + h * 16 + i];
#pragma unroll
            for (int j = 0; j < 16; ++j) {
                float val = 0.f;
#pragma unroll
                for (int i = 0; i < 16; ++i) val += wrow[i] * sW[(h * 16 + i) * 16 + j];
                Ps[c * 136 + h * 16 + j] = f2bf(val);
                pb += val * sv[h * 16 + j];
            }
        }
        red[grp][c] = pb;
    }
    __syncthreads();
    if (t < 128)
        bias2[b * 128 + t] = b_out[t] + red[0][t] + red[1][t] + red[2][t] + red[3][t];

    // M = P @ A  (MFMA: a = P rows, b = A^T rows)
    {
        f32x4 macc[8];
#pragma unroll
        for (int ct = 0; ct < 8; ++ct) macc[ct] = (f32x4){0.f, 0.f, 0.f, 0.f};
#pragma unroll
        for (int ks = 0; ks < 4; ++ks) {
            short8 pf = *(const short8*)&Ts[rA * 136 + ks * 32 + q * 8];
#pragma unroll
            for (int ct = 0; ct < 8; ++ct) {
                short8 atf = *(const short8*)&At[(ct * 16 + i16) * 136 + ks * 32 + q * 8];
                macc[ct] = __builtin_amdgcn_mfma_f32_16x16x32_bf16(pf, atf, macc[ct], 0, 0, 0);
            }
        }
        unsigned short* mb = Mb + (size_t)b * 16384;
#pragma unroll
        for (int ct = 0; ct < 8; ++ct)
#pragma unroll
            for (int r = 0; r < 4; ++r)
                mb[(wv * 16 + q * 4 + r) * 128 + ct * 16 + i16] = f2bf(macc[ct][r]);
    }
}

// ---------------- K3: out = x + M @ x + bias2 ----------------
__global__ __launch_bounds__(256, 4) void k_out(const float* __restrict__ x,
                                                const unsigned short* __restrict__ Mb,
                                                const float* __restrict__ bias2,
                                                float* __restrict__ out) {
    __shared__ unsigned short Xt[128 * 128];   // [p][k] bf16, granule-swizzled
    __shared__ float b2s[128];

    const int t = threadIdx.x;
    const int lane = t & 63, wv = t >> 6;
    const int q = lane >> 4, i16 = lane & 15;
    const int b = blockIdx.x >> 7;
    const int p0 = (blockIdx.x & 127) << 7;

    if (t < 128) b2s[t] = bias2[b * 128 + t];

    const float* xb = x + (size_t)b * (128 * NPOS) + p0;
#pragma unroll
    for (int i = 0; i < 16; ++i) {
        int p = ((i & 1) << 6) + lane;
        int kq = (wv << 3) + (i >> 1);
        const float* col = xb + (size_t)(kq * 4) * NPOS + p;
        float a0 = col[0];
        float a1 = col[NPOS];
        float a2 = col[2 * NPOS];
        float a3 = col[3 * NPOS];
        ushort4 o; o.x = f2bf(a0); o.y = f2bf(a1); o.z = f2bf(a2); o.w = f2bf(a3);
        int g = kq >> 1;
        int sg = g ^ (p & 7);
        *(ushort4*)&Xt[p * 128 + (sg << 3) + ((kq & 1) << 2)] = o;
    }
    __syncthreads();

    f32x4 acc[2][8];
#pragma unroll
    for (int a = 0; a < 2; ++a)
#pragma unroll
        for (int pt = 0; pt < 8; ++pt) acc[a][pt] = (f32x4){0.f, 0.f, 0.f, 0.f};

    const unsigned short* Mrow = Mb + (size_t)b * 16384;
#pragma unroll
    for (int ks = 0; ks < 4; ++ks) {
        short8 a0 = *(const short8*)&Mrow[(wv * 32 + i16) * 128 + ks * 32 + q * 8];
        short8 a1 = *(const short8*)&Mrow[(wv * 32 + 16 + i16) * 128 + ks * 32 + q * 8];
        int g = ks * 4 + q;
#pragma unroll
        for (int pt = 0; pt < 8; ++pt) {
            int pr = pt * 16 + i16;
            short8 bb = *(const short8*)&Xt[pr * 128 + ((g ^ (pr & 7)) << 3)];
            acc[0][pt] = __builtin_amdgcn_mfma_f32_16x16x32_bf16(a0, bb, acc[0][pt], 0, 0, 0);
            acc[1][pt] = __builtin_amdgcn_mfma_f32_16x16x32_bf16(a1, bb, acc[1][pt], 0, 0, 0);
        }
    }

    float* ob = out + (size_t)b * (128 * NPOS) + p0;
#pragma unroll
    for (int a = 0; a < 2; ++a) {
        int cb = wv * 32 + a * 16 + q * 4;
#pragma unroll
        for (int pt = 0; pt < 8; ++pt) {
            int p = pt * 16 + i16;
#pragma unroll
            for (int r = 0; r < 4; ++r) {
                int c = cb + r;
                ob[(size_t)c * NPOS + p] = acc[a][pt][r] + b2s[c] + xb[(size_t)c * NPOS + p];
            }
        }
    }
}

extern "C" void kernel_launch(void* const* d_in, const int* in_sizes, int n_in,
                              void* d_out, int out_size, void* d_ws, size_t ws_size,
                              hipStream_t stream) {
    const float* x    = (const float*)d_in[0];
    const float* gn_w = (const float*)d_in[1];
    const float* gn_b = (const float*)d_in[2];
    const float* w_in = (const float*)d_in[3];
    const float* b_in = (const float*)d_in[4];
    const float* w_out= (const float*)d_in[5];
    const float* b_out= (const float*)d_in[6];
    float* out = (float*)d_out;

    // workspace (bytes), total ~17.7 MB:
    char* ws = (char*)d_ws;
    float* Gpart          = (float*)(ws + 0);          // 256*16384*4 = 16777216
    float* mpart          = (float*)(ws + 16777216);   // 256*128*4   = 131072
    float* G              = (float*)(ws + 16908288);   // 8*16384*4   = 524288
    float* mvG            = (float*)(ws + 17432576);   // 4096
    float* bias2          = (float*)(ws + 17436672);   // 4096
    unsigned short* Mb    = (unsigned short*)(ws + 17440768); // 262144

    k_gram<<<dim3(256), dim3(512), 0, stream>>>(x, Gpart, mpart);
    k_reduce<<<dim3(128), dim3(256), 0, stream>>>(Gpart, mpart, G, mvG);
    k_fold<<<dim3(8), dim3(512), 0, stream>>>(G, mvG, gn_w, gn_b, w_in, b_in,
                                              w_out, b_out, Mb, bias2);
    k_out<<<dim3(1024), dim3(256), 0, stream>>>(x, Mb, bias2, out);
}